// Round 15
// baseline (811.740 us; speedup 1.0000x reference)
//
#include <hip/hip_runtime.h>
#include <hip/hip_bf16.h>
#include <cstdint>

#define B_    2
#define T_    1024
#define E_    1024
#define H_    16
#define HS_   64
#define L_    4
#define V_    32000
#define FF_   4096
#define BT_   2048
#define EPS_  1e-5f
#define SCALE_ 0.03125f   // 1/sqrt(E) = 1/32

typedef __bf16 bf16;
typedef bf16  bf16x4 __attribute__((ext_vector_type(4)));
typedef bf16  bf16x8 __attribute__((ext_vector_type(8)));
typedef float f32x4  __attribute__((ext_vector_type(4)));

#define GL2LDS(gp, lp) __builtin_amdgcn_global_load_lds( \
    (const __attribute__((address_space(1))) void*)(gp), \
    (__attribute__((address_space(3))) void*)(lp), 16, 0, 0)

// ---------------------------------------------------------------- layernorm helper
__device__ __forceinline__ float wred_sum(float v) {
#pragma unroll
  for (int o = 32; o; o >>= 1) v += __shfl_xor(v, o, 64);
  return v;
}

__device__ __forceinline__ void ln_body(
    f32x4 v, const float* g, const float* b, bf16* h, size_t off, int tid)
{
  float s  = v[0] + v[1] + v[2] + v[3];
  float sq = v[0]*v[0] + v[1]*v[1] + v[2]*v[2] + v[3]*v[3];
  s  = wred_sum(s);
  sq = wred_sum(sq);
  __shared__ float rs[4], rq[4];
  int w = tid >> 6, lane = tid & 63;
  if (lane == 0) { rs[w] = s; rq[w] = sq; }
  __syncthreads();
  float S = rs[0] + rs[1] + rs[2] + rs[3];
  float Q = rq[0] + rq[1] + rq[2] + rq[3];
  float mean = S * (1.0f / E_);
  float var  = Q * (1.0f / E_) - mean * mean;
  float rstd = rsqrtf(fmaxf(var, 0.0f) + EPS_);
  f32x4 gv = *(const f32x4*)(g + tid * 4);
  f32x4 bv = *(const f32x4*)(b + tid * 4);
  f32x4 o = (v - mean) * rstd * gv + bv;
  bf16x4 ob = { (bf16)o[0], (bf16)o[1], (bf16)o[2], (bf16)o[3] };
  *(bf16x4*)(h + off) = ob;
}

// ---------------------------------------------------------------- embed + ln1(layer0) fused
__global__ __launch_bounds__(256) void embed_ln_kernel(
    const int* __restrict__ ids, const float* __restrict__ emb,
    const float* __restrict__ pos, const float* __restrict__ g,
    const float* __restrict__ b, float* __restrict__ x, bf16* __restrict__ h)
{
  int bt = blockIdx.x, tid = threadIdx.x;
  int t  = bt & (T_ - 1);
  int id = ids[bt];
  f32x4 e = *(const f32x4*)(emb + (size_t)id * E_ + tid * 4);
  f32x4 p = *(const f32x4*)(pos + (size_t)t  * E_ + tid * 4);
  f32x4 v = e + p;
  size_t off = (size_t)bt * E_ + tid * 4;
  *(f32x4*)(x + off) = v;
  ln_body(v, g, b, h, off, tid);
}

// ---------------------------------------------------------------- layernorm (f32 in, bf16 out)
__global__ __launch_bounds__(256) void ln_kernel(
    const float* __restrict__ x, const float* __restrict__ g,
    const float* __restrict__ b, bf16* __restrict__ h)
{
  int row = blockIdx.x, tid = threadIdx.x;
  size_t off = (size_t)row * E_ + tid * 4;
  f32x4 v = *(const f32x4*)(x + off);
  ln_body(v, g, b, h, off, tid);
}

// ---------------------------------------------------------------- weight transpose+convert (proj)
__global__ __launch_bounds__(256) void convw_kernel(
    const float* __restrict__ W0, bf16* __restrict__ O0, int K, int ldW)
{
  __shared__ float tl[32][33];
  int n0 = blockIdx.x * 32, k0 = blockIdx.y * 32;
  int c = threadIdx.x & 31, r = threadIdx.x >> 5;
#pragma unroll
  for (int p = 0; p < 4; ++p)
    tl[r + p * 8][c] = W0[(size_t)(k0 + r + p * 8) * ldW + n0 + c];
  __syncthreads();
  int n2 = threadIdx.x >> 3, kq = threadIdx.x & 7;
  bf16x4 ov = { (bf16)tl[kq * 4 + 0][n2], (bf16)tl[kq * 4 + 1][n2],
                (bf16)tl[kq * 4 + 2][n2], (bf16)tl[kq * 4 + 3][n2] };
  *(bf16x4*)(O0 + (size_t)(n0 + n2) * K + k0 + kq * 4) = ov;
}

// ---------------------------------------------------------------- fused per-layer weight convert
__global__ __launch_bounds__(256) void convw_all(
    const float* __restrict__ wq, const float* __restrict__ wk,
    const float* __restrict__ wv, const float* __restrict__ w1,
    const float* __restrict__ w2,
    bf16* __restrict__ oq, bf16* __restrict__ ok, bf16* __restrict__ ov,
    bf16* __restrict__ o1, bf16* __restrict__ o2)
{
  int bid = blockIdx.x;
  const float* W; bf16* O; int K, ldW, nx, ny;
  if (bid < 3072) {
    int z = bid >> 10, rem = bid & 1023;
    W = (z == 0) ? wq : (z == 1) ? wk : wv;
    O = (z == 0) ? oq : (z == 1) ? ok : ov;
    K = 1024; ldW = 1024; nx = rem & 31; ny = rem >> 5;
  } else if (bid < 7168) {
    int idx = bid - 3072;
    W = w1; O = o1; K = 1024; ldW = 4096;
    nx = idx & 127; ny = idx >> 7;
  } else {
    int idx = bid - 7168;
    W = w2; O = o2; K = 4096; ldW = 1024;
    nx = idx & 31; ny = idx >> 5;
  }
  __shared__ float tl[32][33];
  int n0 = nx * 32, k0 = ny * 32;
  int c = threadIdx.x & 31, r = threadIdx.x >> 5;
#pragma unroll
  for (int p = 0; p < 4; ++p)
    tl[r + p * 8][c] = W[(size_t)(k0 + r + p * 8) * ldW + n0 + c];
  __syncthreads();
  int n2 = threadIdx.x >> 3, kq = threadIdx.x & 7;
  bf16x4 ovv = { (bf16)tl[kq * 4 + 0][n2], (bf16)tl[kq * 4 + 1][n2],
                 (bf16)tl[kq * 4 + 2][n2], (bf16)tl[kq * 4 + 3][n2] };
  *(bf16x4*)(O + (size_t)(n0 + n2) * K + k0 + kq * 4) = ovv;
}

// ---------------------------------------------------------------- GEMM bf16 MFMA 128x128 (r11-proven)
// MODE 1: bf16 out (+bias, opt GELU). MODE 3: bf16 split-K partial (blockIdx.z).
template <int ACT, int MODE>
__global__ __launch_bounds__(256) void gemm_bf16(
    const bf16* __restrict__ A,
    const bf16* __restrict__ B0, const bf16* __restrict__ B1, const bf16* __restrict__ B2,
    const float* __restrict__ bi0, const float* __restrict__ bi1, const float* __restrict__ bi2,
    bf16* __restrict__ Cb0, bf16* __restrict__ Cb1, bf16* __restrict__ Cb2,
    int K, int ldc, int LDK)
{
  int z = blockIdx.z;
  const bf16*  Bm = (MODE == 3) ? B0 : (z == 0) ? B0 : (z == 1) ? B1 : B2;
  const float* bi = (z == 0) ? bi0 : (z == 1) ? bi1 : bi2;
  bf16*        Cb = (MODE == 3) ? Cb0 : (z == 0) ? Cb0 : (z == 1) ? Cb1 : Cb2;
  int koff = (MODE == 3) ? z * K : 0;

  int nb  = (int)(gridDim.x * gridDim.y);
  int lin = blockIdx.x + gridDim.x * blockIdx.y;
  int per = nb >> 3;
  int b   = (lin & 7) * per + (lin >> 3);
  int mi  = b & 15;
  int ni  = b >> 4;

  __shared__ __align__(16) char lds[2][16384];

  int tid = threadIdx.x;
  int lane = tid & 63, wid = tid >> 6;
  int wm = (wid >> 1) * 64, wn = (wid & 1) * 64;
  int fr = lane & 15, fb = lane >> 4;

  const bf16* Asrc = A  + (size_t)(mi * 128) * LDK + koff;
  const bf16* Bsrc = Bm + (size_t)(ni * 128) * LDK + koff;

  int NT = K >> 5;

#define STAGE_U(buf, kk, is)                                                \
  {                                                                         \
    int rl = (is) * 64 + (tid >> 2);                                        \
    int key = (rl >> 1) & 3;                                                \
    int ck  = ((tid & 3) ^ key) * 8;                                        \
    GL2LDS(Asrc + (size_t)rl * LDK + (kk) + ck,                             \
           lds[buf] + (is) * 4096 + tid * 16);                              \
    GL2LDS(Bsrc + (size_t)rl * LDK + (kk) + ck,                             \
           lds[buf] + 8192 + (is) * 4096 + tid * 16);                       \
  }

  f32x4 acc[4][4];
#pragma unroll
  for (int i = 0; i < 4; ++i)
#pragma unroll
    for (int j = 0; j < 4; ++j) acc[i][j] = (f32x4){0.f, 0.f, 0.f, 0.f};

  STAGE_U(0, 0, 0);
  STAGE_U(0, 0, 1);

  for (int t = 0; t < NT; ++t) {
    int buf = t & 1;
    int nk  = (t + 1) << 5;
    bool pf = (t + 1 < NT);

    if (pf) {
      STAGE_U(buf ^ 1, nk, 0);
      asm volatile("s_waitcnt vmcnt(2)" ::: "memory");
    } else {
      asm volatile("s_waitcnt vmcnt(0)" ::: "memory");
    }
    __builtin_amdgcn_s_barrier();
    asm volatile("" ::: "memory");

    const char* Ab = lds[buf];
    const char* Bb = lds[buf] + 8192;
    bf16x8 af[4], bfr[4];
#pragma unroll
    for (int i = 0; i < 4; ++i) {
      int rl = wm + i * 16 + fr;
      af[i] = *(const bf16x8*)(Ab + rl * 64 + ((fb ^ ((rl >> 1) & 3)) * 16));
    }
#pragma unroll
    for (int j = 0; j < 4; ++j) {
      int rl = wn + j * 16 + fr;
      bfr[j] = *(const bf16x8*)(Bb + rl * 64 + ((fb ^ ((rl >> 1) & 3)) * 16));
    }
    __builtin_amdgcn_s_setprio(1);
#pragma unroll
    for (int i = 0; i < 2; ++i)
#pragma unroll
      for (int j = 0; j < 4; ++j)
        acc[i][j] = __builtin_amdgcn_mfma_f32_16x16x32_bf16(af[i], bfr[j], acc[i][j], 0, 0, 0);
    __builtin_amdgcn_s_setprio(0);
    if (pf) STAGE_U(buf ^ 1, nk, 1);
    __builtin_amdgcn_s_setprio(1);
#pragma unroll
    for (int i = 2; i < 4; ++i)
#pragma unroll
      for (int j = 0; j < 4; ++j)
        acc[i][j] = __builtin_amdgcn_mfma_f32_16x16x32_bf16(af[i], bfr[j], acc[i][j], 0, 0, 0);
    __builtin_amdgcn_s_setprio(0);
    asm volatile("" ::: "memory");
    __builtin_amdgcn_s_barrier();
  }
#undef STAGE_U

  // epilogue: C/D layout col = lane&15, row = (lane>>4)*4 + reg
#pragma unroll
  for (int i = 0; i < 4; ++i) {
#pragma unroll
    for (int j = 0; j < 4; ++j) {
      int gc = ni * 128 + wn + j * 16 + fr;
      float bv = (MODE == 3) ? 0.f : bi[gc];
#pragma unroll
      for (int r = 0; r < 4; ++r) {
        int gr = mi * 128 + wm + i * 16 + fb * 4 + r;
        float vv = acc[i][j][r] + bv;
        if (ACT == 1) vv = 0.5f * vv * (1.0f + erff(vv * 0.70710678118654752f));
        if (MODE == 1) {
          Cb[(size_t)gr * ldc + gc] = (bf16)vv;
        } else {
          Cb[(size_t)(blockIdx.z * BT_ + gr) * ldc + gc] = (bf16)vv;
        }
      }
    }
  }
}

// ---------------------------------------------------------------- FFN2 split-K combine (last layer)
__global__ __launch_bounds__(256) void combine_kernel(
    const bf16* __restrict__ p, const float* __restrict__ bi,
    float* __restrict__ x, bf16* __restrict__ xb)
{
  int row = blockIdx.x, tid = threadIdx.x;
  size_t off = (size_t)row * E_ + tid * 4;
  bf16x4 a4 = *(const bf16x4*)(p + off);
  bf16x4 c4 = *(const bf16x4*)(p + (size_t)BT_ * E_ + off);
  f32x4 bv = *(const f32x4*)(bi + tid * 4);
  f32x4 xv = *(const f32x4*)(x + off);
  f32x4 nv;
#pragma unroll
  for (int e = 0; e < 4; ++e)
    nv[e] = xv[e] + (float)a4[e] + (float)c4[e] + bv[e];
  *(f32x4*)(x + off) = nv;
  bf16x4 ob = { (bf16)nv[0], (bf16)nv[1], (bf16)nv[2], (bf16)nv[3] };
  *(bf16x4*)(xb + off) = ob;
}

// ---------------------------------------------------------------- combine + next-layer ln1 fused
__global__ __launch_bounds__(256) void combine_ln_kernel(
    const bf16* __restrict__ p, const float* __restrict__ bi,
    const float* __restrict__ g, const float* __restrict__ b,
    float* __restrict__ x, bf16* __restrict__ h)
{
  int row = blockIdx.x, tid = threadIdx.x;
  size_t off = (size_t)row * E_ + tid * 4;
  bf16x4 a4 = *(const bf16x4*)(p + off);
  bf16x4 c4 = *(const bf16x4*)(p + (size_t)BT_ * E_ + off);
  f32x4 bv = *(const f32x4*)(bi + tid * 4);
  f32x4 xv = *(const f32x4*)(x + off);
  f32x4 nv;
#pragma unroll
  for (int e = 0; e < 4; ++e)
    nv[e] = xv[e] + (float)a4[e] + (float)c4[e] + bv[e];
  *(f32x4*)(x + off) = nv;
  ln_body(nv, g, b, h, off, tid);
}

// ---------------------------------------------------------------- GEMM bf16 MFMA 256x256, BK=64
// Deep-prefetch phase schedule (derived from r8's consumption pattern):
// stage unit "pair-k" = A-quarter-k + B-quarter-k (2 loads). Phase q of
// tile t consumes A-quarter-q (+ all B at q==0) -> quarter k is dead after
// phase k, so pair-(q-1) of tile t+2 is staged at phase q (after the phase
// barrier: all waves' phase-(q-1) reads provably complete), and pair-3 of
// tile t+1 at phase 0 (last reader: tile t-1 phase 3, two barriers back).
// Exact in-order vmcnt: phase 0 needs B3(t), 6 loads issued after ->
// vmcnt(6); phases 1-3 need A-q(t), 12 after -> vmcnt(12). Prologue
// (t0 pairs 0-3, t1 pairs 0-2) makes the counts exact from tile 0.
// Tiles >= NT-2 drain with vmcnt(0) (skipped stages invalidate counts).
// One barrier per phase. Per phase: vmcnt -> barrier -> stage -> ds_read
// -> lgkmcnt(0) -> setprio(1) 16 MFMA setprio(0).
__global__ __launch_bounds__(512, 2) void gemm256_kernel(
    const bf16* __restrict__ A, const bf16* __restrict__ Bm,
    const float* __restrict__ bi, float* __restrict__ C, int K, int N)
{
  int nwg = (int)gridDim.x;
  int per = nwg >> 3;
  int bid = (int)blockIdx.x;
  int tl  = (bid & 7) * per + (bid >> 3);   // chunked XCD swizzle (nwg%8==0)
  int mi  = tl & 7, ni = tl >> 3;

  __shared__ __align__(16) char lds[2][65536];

  int tid = threadIdx.x;
  int lane = tid & 63, wid = tid >> 6;
  int wr = wid >> 2, wc = wid & 3;          // 2 x 4 waves
  int fr = lane & 15, fb = lane >> 4;

  const bf16* Asrc = A  + (size_t)(mi * 256) * K;
  const bf16* Bsrc = Bm + (size_t)(ni * 256) * K;

  int NT = K >> 6;   // 16

  // pair-kq = A rows {h*128 + 32kq + rq} + B same rows, 2 loads/thread.
  // dest = h*16384 + kq*4096 + (tid&255)*16  (== row_in_half*128 + slot*16)
#define STGP(buf, kk, kq)                                                   \
  {                                                                         \
    int h  = tid >> 8;                                                      \
    int tt = tid & 255;                                                     \
    int rq = tt >> 3;                                                       \
    int row = h * 128 + 32 * (kq) + rq;                                     \
    int ck  = (tid & 7) ^ (rq & 7);                                         \
    GL2LDS(Asrc + (size_t)row * K + (kk) + ck * 8,                          \
           lds[buf] + h * 16384 + (kq) * 4096 + tt * 16);                   \
    GL2LDS(Bsrc + (size_t)row * K + (kk) + ck * 8,                          \
           lds[buf] + 32768 + h * 16384 + (kq) * 4096 + tt * 16);           \
  }

  f32x4 acc[8][4];
#pragma unroll
  for (int i = 0; i < 8; ++i)
#pragma unroll
    for (int j = 0; j < 4; ++j) acc[i][j] = (f32x4){0.f, 0.f, 0.f, 0.f};

  // prologue: tile 0 pairs 0-3, tile 1 pairs 0-2 (pair-3(1) staged at t0.p0)
  STGP(0, 0, 0); STGP(0, 0, 1); STGP(0, 0, 2); STGP(0, 0, 3);
  if (NT > 1) { STGP(1, 64, 0); STGP(1, 64, 1); STGP(1, 64, 2); }

  for (int t = 0; t < NT; ++t) {
    int buf = t & 1;
    const char* Ab = lds[buf];
    const char* Bb = lds[buf] + 32768;
    bf16x8 bfr[4][2];

#pragma unroll
    for (int q = 0; q < 4; ++q) {
      if (t >= NT - 2) {
        asm volatile("s_waitcnt vmcnt(0)" ::: "memory");
      } else if (q == 0) {
        asm volatile("s_waitcnt vmcnt(6)" ::: "memory");
      } else {
        asm volatile("s_waitcnt vmcnt(12)" ::: "memory");
      }
      __builtin_amdgcn_s_barrier();
      asm volatile("" ::: "memory");

      // stage after the barrier (write-safety: regions consumed >= 1 barrier ago)
      if (q == 0) {
        if (t + 1 < NT) STGP(buf ^ 1, (t + 1) << 6, 3);
      } else {
        if (t + 2 < NT) STGP(buf, (t + 2) << 6, q - 1);
      }

      if (q == 0) {
#pragma unroll
        for (int n2 = 0; n2 < 4; ++n2) {
          int row = wc * 64 + n2 * 16 + fr;
#pragma unroll
          for (int ks = 0; ks < 2; ++ks)
            bfr[n2][ks] = *(const bf16x8*)(Bb + (row >> 7) * 16384 + (row & 127) * 128
                                              + ((((ks * 4 + fb) ^ (fr & 7))) << 4));
        }
      }
      bf16x8 af[2][2];
#pragma unroll
      for (int m2 = 0; m2 < 2; ++m2) {
        int ri = (q * 2 + m2) * 16 + fr;    // rows [32q,32q+32) of wave's half
#pragma unroll
        for (int ks = 0; ks < 2; ++ks)
          af[m2][ks] = *(const bf16x8*)(Ab + wr * 16384 + ri * 128
                                           + ((((ks * 4 + fb) ^ (fr & 7))) << 4));
      }
      asm volatile("s_waitcnt lgkmcnt(0)" ::: "memory");
      __builtin_amdgcn_s_setprio(1);
#pragma unroll
      for (int m2 = 0; m2 < 2; ++m2)
#pragma unroll
        for (int n2 = 0; n2 < 4; ++n2)
#pragma unroll
          for (int ks = 0; ks < 2; ++ks)
            acc[q * 2 + m2][n2] = __builtin_amdgcn_mfma_f32_16x16x32_bf16(
                af[m2][ks], bfr[n2][ks], acc[q * 2 + m2][n2], 0, 0, 0);
      __builtin_amdgcn_s_setprio(0);
    }
  }
#undef STGP

#pragma unroll
  for (int i = 0; i < 8; ++i) {
#pragma unroll
    for (int j = 0; j < 4; ++j) {
      int gc = ni * 256 + wc * 64 + j * 16 + fr;
      float bv = bi[gc];
#pragma unroll
      for (int r = 0; r < 4; ++r) {
        int gr = mi * 256 + wr * 128 + i * 16 + fb * 4 + r;
        C[(size_t)gr * N + gc] = acc[i][j][r] + bv;
      }
    }
  }
}

// ---------------------------------------------------------------- attention (bf16 MFMA flash)
// r12/r13-proven: double-buffered K/V, T14 issue-early/write-late, one
// barrier per tile, setprio on MFMA clusters.
__global__ __launch_bounds__(256) void attn_kernel(
    const bf16* __restrict__ q, const bf16* __restrict__ k,
    const bf16* __restrict__ v, float* __restrict__ x)
{
  __shared__ __align__(16) char Ks[2][8192];
  __shared__ __align__(16) char Vs[2][8192];
  __shared__ __align__(16) char Ps[8192];

  int tid = threadIdx.x, lane = tid & 63, w = tid >> 6;
  int qt = (int)gridDim.x - 1 - (int)blockIdx.x;   // heavy first
  int bh = blockIdx.y;
  int b = bh >> 4, h = bh & 15;
  size_t hoff = (size_t)b * T_ * E_ + h * HS_;
  int fr = lane & 15, fb = lane >> 4;

  const int kc_c0 = tid >> 3;
  const int v_row = tid >> 2;
  const int v_d0  = (tid & 3) * 8;

#define STAGE_K(bufi, kt_)                                                  \
  {                                                                         \
    const bf16* kbase = k + hoff + (size_t)((kt_) * 64) * E_;               \
    _Pragma("unroll")                                                       \
    for (int is = 0; is < 2; ++is) {                                        \
      int c = is * 32 + kc_c0;                                              \
      int key = ((c & 7) ^ (c >> 3)) & 7;                                   \
      GL2LDS(kbase + (size_t)c * E_ + (((tid & 7) ^ key) * 8),              \
             Ks[bufi] + is * 4096 + tid * 16);                              \
    }                                                                       \
  }
#define LOAD_V(kt_)                                                         \
  {                                                                         \
    const bf16* vbase = v + hoff + (size_t)((kt_) * 64 + v_row) * E_;       \
    vv0 = *(const bf16x8*)(vbase + v_d0);                                   \
    vv1 = *(const bf16x8*)(vbase + v_d0 + 32);                              \
  }
#define WRITE_V(bufi)                                                       \
  {                                                                         \
    _Pragma("unroll")                                                       \
    for (int p = 0; p < 2; ++p) {                                           \
      bf16x8 vvp = p ? vv1 : vv0;                                           \
      _Pragma("unroll")                                                     \
      for (int e = 0; e < 8; ++e) {                                         \
        int d = v_d0 + p * 32 + e;                                          \
        int key = ((d & 7) ^ (d >> 3)) & 7;                                 \
        *(bf16*)(Vs[bufi] + d * 128 + ((v_row * 2) ^ (key << 4))) = vvp[e]; \
      }                                                                     \
    }                                                                       \
  }

  bf16x8 qa[2];
  {
    const bf16* qp = q + hoff + (size_t)(qt * 64 + w * 16 + fr) * E_ + fb * 8;
    qa[0] = *(const bf16x8*)qp;
    qa[1] = *(const bf16x8*)(qp + 32);
  }

  f32x4 O[4];
  float m_[4], l_[4];
#pragma unroll
  for (int i = 0; i < 4; ++i) { O[i] = (f32x4){0.f,0.f,0.f,0.f}; m_[i] = -1e30f; l_[i] = 0.f; }

  bf16x8 vv0, vv1;

  STAGE_K(0, 0);
  LOAD_V(0);
  asm volatile("s_waitcnt vmcnt(0)" ::: "memory");
  WRITE_V(0);
  __syncthreads();

  for (int kt = 0; kt <= qt; ++kt) {
    int buf = kt & 1;
    bool pf = (kt < qt);

    f32x4 s[4];
    __builtin_amdgcn_s_setprio(1);
#pragma unroll
    for (int jc = 0; jc < 4; ++jc) {
      s[jc] = (f32x4){0.f, 0.f, 0.f, 0.f};
#pragma unroll
      for (int kc = 0; kc < 2; ++kc) {
        int c = jc * 16 + fr;
        int key = ((c & 7) ^ (c >> 3)) & 7;
        bf16x8 kf = *(const bf16x8*)(Ks[buf] + c * 128 + ((kc * 64 + fb * 16) ^ (key << 4)));
        s[jc] = __builtin_amdgcn_mfma_f32_16x16x32_bf16(qa[kc], kf, s[jc], 0, 0, 0);
      }
    }
    __builtin_amdgcn_s_setprio(0);

    if (pf) {
      STAGE_K(buf ^ 1, kt + 1);
      LOAD_V(kt + 1);
    }

    char* pbase = Ps + w * 2048;
#pragma unroll
    for (int r = 0; r < 4; ++r) {
      float s0 = s[0][r] * SCALE_, s1 = s[1][r] * SCALE_;
      float s2 = s[2][r] * SCALE_, s3 = s[3][r] * SCALE_;
      int qrow = qt * 64 + w * 16 + fb * 4 + r;
      if (kt == qt) {
        int kc0 = kt * 64 + fr;
        if (kc0      > qrow) s0 = -1e30f;
        if (kc0 + 16 > qrow) s1 = -1e30f;
        if (kc0 + 32 > qrow) s2 = -1e30f;
        if (kc0 + 48 > qrow) s3 = -1e30f;
      }
      float mx = fmaxf(fmaxf(s0, s1), fmaxf(s2, s3));
      mx = fmaxf(mx, __shfl_xor(mx, 1, 16));
      mx = fmaxf(mx, __shfl_xor(mx, 2, 16));
      mx = fmaxf(mx, __shfl_xor(mx, 4, 16));
      mx = fmaxf(mx, __shfl_xor(mx, 8, 16));
      float mnew = fmaxf(m_[r], mx);
      float p0 = __expf(s0 - mnew), p1 = __expf(s1 - mnew);
      float p2 = __expf(s2 - mnew), p3 = __expf(s3 - mnew);
      float rs = p0 + p1 + p2 + p3;
      rs += __shfl_xor(rs, 1, 16);
      rs += __shfl_xor(rs, 2, 16);
      rs += __shfl_xor(rs, 4, 16);
      rs += __shfl_xor(rs, 8, 16);
      float scl = __expf(m_[r] - mnew);
      l_[r] = l_[r] * scl + rs;
      m_[r] = mnew;
#pragma unroll
      for (int jd = 0; jd < 4; ++jd) O[jd][r] *= scl;
      int key2 = (r << 4) ^ (fb << 5);
      char* pr_ = pbase + (fb * 4 + r) * 128;
      *(bf16*)(pr_ + (( 0 + fr * 2) ^ key2)) = (bf16)p0;
      *(bf16*)(pr_ + ((32 + fr * 2) ^ key2)) = (bf16)p1;
      *(bf16*)(pr_ + ((64 + fr * 2) ^ key2)) = (bf16)p2;
      *(bf16*)(pr_ + ((96 + fr * 2) ^ key2)) = (bf16)p3;
    }

    __builtin_amdgcn_s_setprio(1);
#pragma unroll
    for (int kc = 0; kc < 2; ++kc) {
      int key2 = ((fr & 3) << 4) ^ ((fr >> 2) << 5);
      bf16x8 pa = *(const bf16x8*)(pbase + fr * 128 + ((kc * 64 + fb * 16) ^ key2));
#pragma unroll
      for (int jd = 0; jd < 4; ++jd) {
        int d = jd * 16 + fr;
        int key = ((d & 7) ^ (d >> 3)) & 7;
        bf16x8 vf = *(const bf16x8*)(Vs[buf] + d * 128 + ((kc * 64 + fb * 16) ^ (key << 4)));
        O[jd] = __builtin_amdgcn_mfma_f32_16x16x32_bf16(pa, vf, O[jd], 0, 0, 0);
      }
    }
    __builtin_amdgcn_s_setprio(0);

    if (pf) {
      asm volatile("s_waitcnt vmcnt(0)" ::: "memory");
      WRITE_V(buf ^ 1);
    }
    __syncthreads();
  }
#undef STAGE_K
#undef LOAD_V
#undef WRITE_V

#pragma unroll
  for (int r = 0; r < 4; ++r) {
    float inv = 1.0f / l_[r];
    float* xp = x + hoff + (size_t)(qt * 64 + w * 16 + fb * 4 + r) * E_;
#pragma unroll
    for (int jd = 0; jd < 4; ++jd) {
      int d = jd * 16 + fr;
      xp[d] += O[jd][r] * inv;
    }
  }
}

// ---------------------------------------------------------------- launch
extern "C" void kernel_launch(void* const* d_in, const int* in_sizes, int n_in,
                              void* d_out, int out_size, void* d_ws, size_t ws_size,
                              hipStream_t stream)
{
  const int*   ids  = (const int*)  d_in[0];
  const float* emb  = (const float*)d_in[1];
  const float* pos  = (const float*)d_in[2];
  const float* wq   = (const float*)d_in[3];
  const float* bq   = (const float*)d_in[4];
  const float* wk   = (const float*)d_in[5];
  const float* bk   = (const float*)d_in[6];
  const float* wv   = (const float*)d_in[7];
  const float* bv   = (const float*)d_in[8];
  const float* w1   = (const float*)d_in[9];
  const float* b1   = (const float*)d_in[10];
  const float* w2   = (const float*)d_in[11];
  const float* b2   = (const float*)d_in[12];
  const float* ln1g = (const float*)d_in[13];
  const float* ln1b = (const float*)d_in[14];
  const float* ln2g = (const float*)d_in[15];
  const float* ln2b = (const float*)d_in[16];
  const float* pw   = (const float*)d_in[17];
  const float* pb   = (const float*)d_in[18];
  float* out = (float*)d_out;

  // ws layout (f32 units), non-overlapping in time:
  //   x   [ 0M,  2M)  f32  BTxE
  //   hb  [ 2M,  3M)  bf16 BTxE      } fpb [2M,4M) = 2 bf16 partials
  //   qb  [ 3M,  4M)  bf16 BTxE      }   (hb,qb dead at FFN2 time)
  //   kb  [ 4M,  5M)  bf16 BTxE
  //   vb  [ 5M,  6M)  bf16 BTxE
  //   ffb [ 6M, 10M)  bf16 BTxFF
  //   lwb [10M,15.5M) bf16 layer weights
  //   hb2 [15.5M,16M) bf16 BTxE  (dead at proj time)
  //   xb  [16M, 17M)  bf16 BTxE
  //   pwb [ 0M,15.625M) bf16 proj weight (all below dead at proj time)
  if (ws_size < (size_t)17 * 1024 * 1024 * 4) return;
  float* ws = (float*)d_ws;
  float* x   = ws;
  bf16*  hb  = (bf16*)(ws + (size_t) 2 * 1024 * 1024);
  bf16*  qb  = (bf16*)(ws + (size_t) 3 * 1024 * 1024);
  bf16*  kb  = (bf16*)(ws + (size_t) 4 * 1024 * 1024);
  bf16*  vb  = (bf16*)(ws + (size_t) 5 * 1024 * 1024);
  bf16*  ffb = (bf16*)(ws + (size_t) 6 * 1024 * 1024);
  bf16*  fpb = (bf16*)(ws + (size_t)2 * 1024 * 1024);
  bf16*  lwb = (bf16*)(ws + (size_t)10 * 1024 * 1024);
  bf16*  hb2 = (bf16*)(ws + (size_t)15 * 1024 * 1024 + 512 * 1024);
  bf16*  xb  = (bf16*)(ws + (size_t)16 * 1024 * 1024);
  bf16*  pwb = (bf16*)ws;
  bf16*  wqt = lwb;
  bf16*  wkt = lwb + (size_t)1 * 1024 * 1024;
  bf16*  wvt = lwb + (size_t)2 * 1024 * 1024;
  bf16*  w1t = lwb + (size_t)3 * 1024 * 1024;
  bf16*  w2t = lwb + (size_t)7 * 1024 * 1024;

  embed_ln_kernel<<<BT_, 256, 0, stream>>>(ids, emb, pos, ln1g, ln1b, x, hb);

  for (int l = 0; l < L_; ++l) {
    const size_t lEE = (size_t)l * E_ * E_;
    const size_t lEF = (size_t)l * E_ * FF_;
    const bf16* hcur = (l == 0) ? hb : hb2;

    convw_all<<<11264, 256, 0, stream>>>(
        wq + lEE, wk + lEE, wv + lEE, w1 + lEF, w2 + lEF,
        wqt, wkt, wvt, w1t, w2t);

    gemm_bf16<0,1><<<dim3(16, E_/128, 3), 256, 0, stream>>>(
        hcur, wqt, wkt, wvt, bq + l*E_, bk + l*E_, bv + l*E_,
        qb, kb, vb, E_, E_, E_);

    attn_kernel<<<dim3(T_/64, B_*H_), 256, 0, stream>>>(qb, kb, vb, x);

    ln_kernel<<<BT_, 256, 0, stream>>>(x, ln2g + l*E_, ln2b + l*E_, hb);

    gemm_bf16<1,1><<<dim3(16, FF_/128, 1), 256, 0, stream>>>(
        hb, w1t, nullptr, nullptr, b1 + (size_t)l*FF_, nullptr, nullptr,
        ffb, nullptr, nullptr, E_, FF_, E_);

    gemm_bf16<0,3><<<dim3(16, E_/128, 2), 256, 0, stream>>>(
        ffb, w2t, nullptr, nullptr, nullptr, nullptr, nullptr,
        fpb, nullptr, nullptr, FF_/2, E_, FF_);
    if (l < L_ - 1) {
      combine_ln_kernel<<<BT_, 256, 0, stream>>>(
          fpb, b2 + l*E_, ln1g + (l+1)*E_, ln1b + (l+1)*E_, x, hb2);
    } else {
      combine_kernel<<<BT_, 256, 0, stream>>>(fpb, b2 + l*E_, x, xb);
    }
  }

  // final projection: whole weight converted, 256^2 BK=64 deep-prefetch GEMM
  convw_kernel<<<dim3(V_/32, E_/32), 256, 0, stream>>>(pw, pwb, E_, V_);
  gemm256_kernel<<<(V_/256) * 8, 512, 0, stream>>>(
      xb, pwb, pb, out, E_, V_);
}

// Round 16
// 801.719 us; speedup vs baseline: 1.0125x; 1.0125x over previous
//
#include <hip/hip_runtime.h>
#include <hip/hip_bf16.h>
#include <cstdint>

#define B_    2
#define T_    1024
#define E_    1024
#define H_    16
#define HS_   64
#define L_    4
#define V_    32000
#define FF_   4096
#define BT_   2048
#define EPS_  1e-5f
#define SCALE_ 0.03125f   // 1/sqrt(E) = 1/32

typedef __bf16 bf16;
typedef bf16  bf16x4 __attribute__((ext_vector_type(4)));
typedef bf16  bf16x8 __attribute__((ext_vector_type(8)));
typedef float f32x4  __attribute__((ext_vector_type(4)));

#define GL2LDS(gp, lp) __builtin_amdgcn_global_load_lds( \
    (const __attribute__((address_space(1))) void*)(gp), \
    (__attribute__((address_space(3))) void*)(lp), 16, 0, 0)

// ---------------------------------------------------------------- layernorm helper
__device__ __forceinline__ float wred_sum(float v) {
#pragma unroll
  for (int o = 32; o; o >>= 1) v += __shfl_xor(v, o, 64);
  return v;
}

__device__ __forceinline__ void ln_body(
    f32x4 v, const float* g, const float* b, bf16* h, size_t off, int tid)
{
  float s  = v[0] + v[1] + v[2] + v[3];
  float sq = v[0]*v[0] + v[1]*v[1] + v[2]*v[2] + v[3]*v[3];
  s  = wred_sum(s);
  sq = wred_sum(sq);
  __shared__ float rs[4], rq[4];
  int w = tid >> 6, lane = tid & 63;
  if (lane == 0) { rs[w] = s; rq[w] = sq; }
  __syncthreads();
  float S = rs[0] + rs[1] + rs[2] + rs[3];
  float Q = rq[0] + rq[1] + rq[2] + rq[3];
  float mean = S * (1.0f / E_);
  float var  = Q * (1.0f / E_) - mean * mean;
  float rstd = rsqrtf(fmaxf(var, 0.0f) + EPS_);
  f32x4 gv = *(const f32x4*)(g + tid * 4);
  f32x4 bv = *(const f32x4*)(b + tid * 4);
  f32x4 o = (v - mean) * rstd * gv + bv;
  bf16x4 ob = { (bf16)o[0], (bf16)o[1], (bf16)o[2], (bf16)o[3] };
  *(bf16x4*)(h + off) = ob;
}

// ---------------------------------------------------------------- embed + ln1(layer0) fused
__global__ __launch_bounds__(256) void embed_ln_kernel(
    const int* __restrict__ ids, const float* __restrict__ emb,
    const float* __restrict__ pos, const float* __restrict__ g,
    const float* __restrict__ b, float* __restrict__ x, bf16* __restrict__ h)
{
  int bt = blockIdx.x, tid = threadIdx.x;
  int t  = bt & (T_ - 1);
  int id = ids[bt];
  f32x4 e = *(const f32x4*)(emb + (size_t)id * E_ + tid * 4);
  f32x4 p = *(const f32x4*)(pos + (size_t)t  * E_ + tid * 4);
  f32x4 v = e + p;
  size_t off = (size_t)bt * E_ + tid * 4;
  *(f32x4*)(x + off) = v;
  ln_body(v, g, b, h, off, tid);
}

// ---------------------------------------------------------------- layernorm (f32 in, bf16 out)
__global__ __launch_bounds__(256) void ln_kernel(
    const float* __restrict__ x, const float* __restrict__ g,
    const float* __restrict__ b, bf16* __restrict__ h)
{
  int row = blockIdx.x, tid = threadIdx.x;
  size_t off = (size_t)row * E_ + tid * 4;
  f32x4 v = *(const f32x4*)(x + off);
  ln_body(v, g, b, h, off, tid);
}

// ---------------------------------------------------------------- weight transpose+convert (proj)
__global__ __launch_bounds__(256) void convw_kernel(
    const float* __restrict__ W0, bf16* __restrict__ O0, int K, int ldW)
{
  __shared__ float tl[32][33];
  int n0 = blockIdx.x * 32, k0 = blockIdx.y * 32;
  int c = threadIdx.x & 31, r = threadIdx.x >> 5;
#pragma unroll
  for (int p = 0; p < 4; ++p)
    tl[r + p * 8][c] = W0[(size_t)(k0 + r + p * 8) * ldW + n0 + c];
  __syncthreads();
  int n2 = threadIdx.x >> 3, kq = threadIdx.x & 7;
  bf16x4 ov = { (bf16)tl[kq * 4 + 0][n2], (bf16)tl[kq * 4 + 1][n2],
                (bf16)tl[kq * 4 + 2][n2], (bf16)tl[kq * 4 + 3][n2] };
  *(bf16x4*)(O0 + (size_t)(n0 + n2) * K + k0 + kq * 4) = ov;
}

// ---------------------------------------------------------------- fused per-layer weight convert
__global__ __launch_bounds__(256) void convw_all(
    const float* __restrict__ wq, const float* __restrict__ wk,
    const float* __restrict__ wv, const float* __restrict__ w1,
    const float* __restrict__ w2,
    bf16* __restrict__ oq, bf16* __restrict__ ok, bf16* __restrict__ ov,
    bf16* __restrict__ o1, bf16* __restrict__ o2)
{
  int bid = blockIdx.x;
  const float* W; bf16* O; int K, ldW, nx, ny;
  if (bid < 3072) {
    int z = bid >> 10, rem = bid & 1023;
    W = (z == 0) ? wq : (z == 1) ? wk : wv;
    O = (z == 0) ? oq : (z == 1) ? ok : ov;
    K = 1024; ldW = 1024; nx = rem & 31; ny = rem >> 5;
  } else if (bid < 7168) {
    int idx = bid - 3072;
    W = w1; O = o1; K = 1024; ldW = 4096;
    nx = idx & 127; ny = idx >> 7;
  } else {
    int idx = bid - 7168;
    W = w2; O = o2; K = 4096; ldW = 1024;
    nx = idx & 31; ny = idx >> 5;
  }
  __shared__ float tl[32][33];
  int n0 = nx * 32, k0 = ny * 32;
  int c = threadIdx.x & 31, r = threadIdx.x >> 5;
#pragma unroll
  for (int p = 0; p < 4; ++p)
    tl[r + p * 8][c] = W[(size_t)(k0 + r + p * 8) * ldW + n0 + c];
  __syncthreads();
  int n2 = threadIdx.x >> 3, kq = threadIdx.x & 7;
  bf16x4 ovv = { (bf16)tl[kq * 4 + 0][n2], (bf16)tl[kq * 4 + 1][n2],
                 (bf16)tl[kq * 4 + 2][n2], (bf16)tl[kq * 4 + 3][n2] };
  *(bf16x4*)(O + (size_t)(n0 + n2) * K + k0 + kq * 4) = ovv;
}

// ---------------------------------------------------------------- GEMM bf16 MFMA 128x128 (r11-proven)
// MODE 1: bf16 out (+bias, opt GELU). MODE 3: bf16 split-K partial (blockIdx.z).
template <int ACT, int MODE>
__global__ __launch_bounds__(256) void gemm_bf16(
    const bf16* __restrict__ A,
    const bf16* __restrict__ B0, const bf16* __restrict__ B1, const bf16* __restrict__ B2,
    const float* __restrict__ bi0, const float* __restrict__ bi1, const float* __restrict__ bi2,
    bf16* __restrict__ Cb0, bf16* __restrict__ Cb1, bf16* __restrict__ Cb2,
    int K, int ldc, int LDK)
{
  int z = blockIdx.z;
  const bf16*  Bm = (MODE == 3) ? B0 : (z == 0) ? B0 : (z == 1) ? B1 : B2;
  const float* bi = (z == 0) ? bi0 : (z == 1) ? bi1 : bi2;
  bf16*        Cb = (MODE == 3) ? Cb0 : (z == 0) ? Cb0 : (z == 1) ? Cb1 : Cb2;
  int koff = (MODE == 3) ? z * K : 0;

  int nb  = (int)(gridDim.x * gridDim.y);
  int lin = blockIdx.x + gridDim.x * blockIdx.y;
  int per = nb >> 3;
  int b   = (lin & 7) * per + (lin >> 3);
  int mi  = b & 15;
  int ni  = b >> 4;

  __shared__ __align__(16) char lds[2][16384];

  int tid = threadIdx.x;
  int lane = tid & 63, wid = tid >> 6;
  int wm = (wid >> 1) * 64, wn = (wid & 1) * 64;
  int fr = lane & 15, fb = lane >> 4;

  const bf16* Asrc = A  + (size_t)(mi * 128) * LDK + koff;
  const bf16* Bsrc = Bm + (size_t)(ni * 128) * LDK + koff;

  int NT = K >> 5;

#define STAGE_U(buf, kk, is)                                                \
  {                                                                         \
    int rl = (is) * 64 + (tid >> 2);                                        \
    int key = (rl >> 1) & 3;                                                \
    int ck  = ((tid & 3) ^ key) * 8;                                        \
    GL2LDS(Asrc + (size_t)rl * LDK + (kk) + ck,                             \
           lds[buf] + (is) * 4096 + tid * 16);                              \
    GL2LDS(Bsrc + (size_t)rl * LDK + (kk) + ck,                             \
           lds[buf] + 8192 + (is) * 4096 + tid * 16);                       \
  }

  f32x4 acc[4][4];
#pragma unroll
  for (int i = 0; i < 4; ++i)
#pragma unroll
    for (int j = 0; j < 4; ++j) acc[i][j] = (f32x4){0.f, 0.f, 0.f, 0.f};

  STAGE_U(0, 0, 0);
  STAGE_U(0, 0, 1);

  for (int t = 0; t < NT; ++t) {
    int buf = t & 1;
    int nk  = (t + 1) << 5;
    bool pf = (t + 1 < NT);

    if (pf) {
      STAGE_U(buf ^ 1, nk, 0);
      asm volatile("s_waitcnt vmcnt(2)" ::: "memory");
    } else {
      asm volatile("s_waitcnt vmcnt(0)" ::: "memory");
    }
    __builtin_amdgcn_s_barrier();
    asm volatile("" ::: "memory");

    const char* Ab = lds[buf];
    const char* Bb = lds[buf] + 8192;
    bf16x8 af[4], bfr[4];
#pragma unroll
    for (int i = 0; i < 4; ++i) {
      int rl = wm + i * 16 + fr;
      af[i] = *(const bf16x8*)(Ab + rl * 64 + ((fb ^ ((rl >> 1) & 3)) * 16));
    }
#pragma unroll
    for (int j = 0; j < 4; ++j) {
      int rl = wn + j * 16 + fr;
      bfr[j] = *(const bf16x8*)(Bb + rl * 64 + ((fb ^ ((rl >> 1) & 3)) * 16));
    }
    __builtin_amdgcn_s_setprio(1);
#pragma unroll
    for (int i = 0; i < 2; ++i)
#pragma unroll
      for (int j = 0; j < 4; ++j)
        acc[i][j] = __builtin_amdgcn_mfma_f32_16x16x32_bf16(af[i], bfr[j], acc[i][j], 0, 0, 0);
    __builtin_amdgcn_s_setprio(0);
    if (pf) STAGE_U(buf ^ 1, nk, 1);
    __builtin_amdgcn_s_setprio(1);
#pragma unroll
    for (int i = 2; i < 4; ++i)
#pragma unroll
      for (int j = 0; j < 4; ++j)
        acc[i][j] = __builtin_amdgcn_mfma_f32_16x16x32_bf16(af[i], bfr[j], acc[i][j], 0, 0, 0);
    __builtin_amdgcn_s_setprio(0);
    asm volatile("" ::: "memory");
    __builtin_amdgcn_s_barrier();
  }
#undef STAGE_U

  // epilogue: C/D layout col = lane&15, row = (lane>>4)*4 + reg
#pragma unroll
  for (int i = 0; i < 4; ++i) {
#pragma unroll
    for (int j = 0; j < 4; ++j) {
      int gc = ni * 128 + wn + j * 16 + fr;
      float bv = (MODE == 3) ? 0.f : bi[gc];
#pragma unroll
      for (int r = 0; r < 4; ++r) {
        int gr = mi * 128 + wm + i * 16 + fb * 4 + r;
        float vv = acc[i][j][r] + bv;
        if (ACT == 1) vv = 0.5f * vv * (1.0f + erff(vv * 0.70710678118654752f));
        if (MODE == 1) {
          Cb[(size_t)gr * ldc + gc] = (bf16)vv;
        } else {
          Cb[(size_t)(blockIdx.z * BT_ + gr) * ldc + gc] = (bf16)vv;
        }
      }
    }
  }
}

// ---------------------------------------------------------------- FFN2 split-K combine (last layer)
__global__ __launch_bounds__(256) void combine_kernel(
    const bf16* __restrict__ p, const float* __restrict__ bi,
    float* __restrict__ x, bf16* __restrict__ xb)
{
  int row = blockIdx.x, tid = threadIdx.x;
  size_t off = (size_t)row * E_ + tid * 4;
  bf16x4 a4 = *(const bf16x4*)(p + off);
  bf16x4 c4 = *(const bf16x4*)(p + (size_t)BT_ * E_ + off);
  f32x4 bv = *(const f32x4*)(bi + tid * 4);
  f32x4 xv = *(const f32x4*)(x + off);
  f32x4 nv;
#pragma unroll
  for (int e = 0; e < 4; ++e)
    nv[e] = xv[e] + (float)a4[e] + (float)c4[e] + bv[e];
  *(f32x4*)(x + off) = nv;
  bf16x4 ob = { (bf16)nv[0], (bf16)nv[1], (bf16)nv[2], (bf16)nv[3] };
  *(bf16x4*)(xb + off) = ob;
}

// ---------------------------------------------------------------- combine + next-layer ln1 fused
__global__ __launch_bounds__(256) void combine_ln_kernel(
    const bf16* __restrict__ p, const float* __restrict__ bi,
    const float* __restrict__ g, const float* __restrict__ b,
    float* __restrict__ x, bf16* __restrict__ h)
{
  int row = blockIdx.x, tid = threadIdx.x;
  size_t off = (size_t)row * E_ + tid * 4;
  bf16x4 a4 = *(const bf16x4*)(p + off);
  bf16x4 c4 = *(const bf16x4*)(p + (size_t)BT_ * E_ + off);
  f32x4 bv = *(const f32x4*)(bi + tid * 4);
  f32x4 xv = *(const f32x4*)(x + off);
  f32x4 nv;
#pragma unroll
  for (int e = 0; e < 4; ++e)
    nv[e] = xv[e] + (float)a4[e] + (float)c4[e] + bv[e];
  *(f32x4*)(x + off) = nv;
  ln_body(nv, g, b, h, off, tid);
}

// ---------------------------------------------------------------- GEMM bf16 MFMA 256x256, BK=64
// (round-8 proven version, 157us / 35.5% MfmaUtil — best of 4 tested
// schedules; r7 depth-3, r9 per-phase, r15 deep-prefetch all regressed)
__global__ __launch_bounds__(512, 2) void gemm256_kernel(
    const bf16* __restrict__ A, const bf16* __restrict__ Bm,
    const float* __restrict__ bi, float* __restrict__ C, int K, int N)
{
  int nwg = (int)gridDim.x;
  int per = nwg >> 3;
  int bid = (int)blockIdx.x;
  int tl  = (bid & 7) * per + (bid >> 3);   // chunked XCD swizzle (nwg%8==0)
  int mi  = tl & 7, ni = tl >> 3;

  __shared__ __align__(16) char lds[2][65536];

  int tid = threadIdx.x;
  int lane = tid & 63, wid = tid >> 6;
  int wr = wid >> 2, wc = wid & 3;          // 2 x 4 waves
  int fr = lane & 15, fb = lane >> 4;

  const bf16* Asrc = A  + (size_t)(mi * 256) * K;
  const bf16* Bsrc = Bm + (size_t)(ni * 256) * K;

  int NT = K >> 6;   // 16

  // one quarter = (h, is): 64 rows x 64 cols of A and of B (8 KB each)
#define STGQ(buf, kk, h, is)                                               \
  {                                                                        \
    int ri  = (is) * 64 + (tid >> 3);                                      \
    int ck  = (tid & 7) ^ (ri & 7);                                        \
    int row = (h) * 128 + ri;                                              \
    GL2LDS(Asrc + (size_t)row * K + (kk) + ck * 8,                         \
           lds[buf] + (h) * 16384 + (is) * 8192 + tid * 16);               \
    GL2LDS(Bsrc + (size_t)row * K + (kk) + ck * 8,                         \
           lds[buf] + 32768 + (h) * 16384 + (is) * 8192 + tid * 16);       \
  }

  f32x4 acc[8][4];
#pragma unroll
  for (int i = 0; i < 8; ++i)
#pragma unroll
    for (int j = 0; j < 4; ++j) acc[i][j] = (f32x4){0.f, 0.f, 0.f, 0.f};

  // prologue: stage tile 0 fully (8 loads)
  STGQ(0, 0, 0, 0); STGQ(0, 0, 0, 1); STGQ(0, 0, 1, 0); STGQ(0, 0, 1, 1);

  for (int t = 0; t < NT; ++t) {
    int buf = t & 1;
    int nk  = (t + 1) << 6;
    bool pf = (t + 1 < NT);

    if (pf) {
      STGQ(buf ^ 1, nk, 0, 0);
      asm volatile("s_waitcnt vmcnt(2)" ::: "memory");   // tile t landed
    } else {
      asm volatile("s_waitcnt vmcnt(0)" ::: "memory");
    }
    __builtin_amdgcn_s_barrier();
    asm volatile("" ::: "memory");

    const char* Ab = lds[buf];
    const char* Bb = lds[buf] + 32768;

    bf16x8 bfr[4][2];
#pragma unroll
    for (int n2 = 0; n2 < 4; ++n2) {
      int row = wc * 64 + n2 * 16 + fr;
#pragma unroll
      for (int ks = 0; ks < 2; ++ks)
        bfr[n2][ks] = *(const bf16x8*)(Bb + (row >> 7) * 16384 + (row & 127) * 128
                                          + ((((ks * 4 + fb) ^ (fr & 7))) << 4));
    }

#pragma unroll
    for (int q = 0; q < 4; ++q) {
      bf16x8 af[2][2];
#pragma unroll
      for (int m2 = 0; m2 < 2; ++m2) {
        int ri = (q * 2 + m2) * 16 + fr;
#pragma unroll
        for (int ks = 0; ks < 2; ++ks)
          af[m2][ks] = *(const bf16x8*)(Ab + wr * 16384 + ri * 128
                                           + ((((ks * 4 + fb) ^ (fr & 7))) << 4));
      }
      __builtin_amdgcn_s_setprio(1);
#pragma unroll
      for (int m2 = 0; m2 < 2; ++m2)
#pragma unroll
        for (int n2 = 0; n2 < 4; ++n2)
#pragma unroll
          for (int ks = 0; ks < 2; ++ks)
            acc[q * 2 + m2][n2] = __builtin_amdgcn_mfma_f32_16x16x32_bf16(
                af[m2][ks], bfr[n2][ks], acc[q * 2 + m2][n2], 0, 0, 0);
      __builtin_amdgcn_s_setprio(0);
      // interleave the next stage quarter between MFMA clusters
      if (pf && q == 0) STGQ(buf ^ 1, nk, 0, 1);
      if (pf && q == 1) STGQ(buf ^ 1, nk, 1, 0);
      if (pf && q == 2) STGQ(buf ^ 1, nk, 1, 1);
    }
    asm volatile("" ::: "memory");
    __builtin_amdgcn_s_barrier();   // reads of buf done before next step stages over it
  }
#undef STGQ

#pragma unroll
  for (int i = 0; i < 8; ++i) {
#pragma unroll
    for (int j = 0; j < 4; ++j) {
      int gc = ni * 256 + wc * 64 + j * 16 + fr;
      float bv = bi[gc];
#pragma unroll
      for (int r = 0; r < 4; ++r) {
        int gr = mi * 256 + wr * 128 + i * 16 + fb * 4 + r;
        C[(size_t)gr * N + gc] = acc[i][j][r] + bv;
      }
    }
  }
}

// ---------------------------------------------------------------- attention (bf16 MFMA flash)
// r12/r13-proven: double-buffered K/V, T14 issue-early/write-late, one
// barrier per tile, setprio on MFMA clusters.
__global__ __launch_bounds__(256) void attn_kernel(
    const bf16* __restrict__ q, const bf16* __restrict__ k,
    const bf16* __restrict__ v, float* __restrict__ x)
{
  __shared__ __align__(16) char Ks[2][8192];
  __shared__ __align__(16) char Vs[2][8192];
  __shared__ __align__(16) char Ps[8192];

  int tid = threadIdx.x, lane = tid & 63, w = tid >> 6;
  int qt = (int)gridDim.x - 1 - (int)blockIdx.x;   // heavy first
  int bh = blockIdx.y;
  int b = bh >> 4, h = bh & 15;
  size_t hoff = (size_t)b * T_ * E_ + h * HS_;
  int fr = lane & 15, fb = lane >> 4;

  const int kc_c0 = tid >> 3;
  const int v_row = tid >> 2;
  const int v_d0  = (tid & 3) * 8;

#define STAGE_K(bufi, kt_)                                                  \
  {                                                                         \
    const bf16* kbase = k + hoff + (size_t)((kt_) * 64) * E_;               \
    _Pragma("unroll")                                                       \
    for (int is = 0; is < 2; ++is) {                                        \
      int c = is * 32 + kc_c0;                                              \
      int key = ((c & 7) ^ (c >> 3)) & 7;                                   \
      GL2LDS(kbase + (size_t)c * E_ + (((tid & 7) ^ key) * 8),              \
             Ks[bufi] + is * 4096 + tid * 16);                              \
    }                                                                       \
  }
#define LOAD_V(kt_)                                                         \
  {                                                                         \
    const bf16* vbase = v + hoff + (size_t)((kt_) * 64 + v_row) * E_;       \
    vv0 = *(const bf16x8*)(vbase + v_d0);                                   \
    vv1 = *(const bf16x8*)(vbase + v_d0 + 32);                              \
  }
#define WRITE_V(bufi)                                                       \
  {                                                                         \
    _Pragma("unroll")                                                       \
    for (int p = 0; p < 2; ++p) {                                           \
      bf16x8 vvp = p ? vv1 : vv0;                                           \
      _Pragma("unroll")                                                     \
      for (int e = 0; e < 8; ++e) {                                         \
        int d = v_d0 + p * 32 + e;                                          \
        int key = ((d & 7) ^ (d >> 3)) & 7;                                 \
        *(bf16*)(Vs[bufi] + d * 128 + ((v_row * 2) ^ (key << 4))) = vvp[e]; \
      }                                                                     \
    }                                                                       \
  }

  bf16x8 qa[2];
  {
    const bf16* qp = q + hoff + (size_t)(qt * 64 + w * 16 + fr) * E_ + fb * 8;
    qa[0] = *(const bf16x8*)qp;
    qa[1] = *(const bf16x8*)(qp + 32);
  }

  f32x4 O[4];
  float m_[4], l_[4];
#pragma unroll
  for (int i = 0; i < 4; ++i) { O[i] = (f32x4){0.f,0.f,0.f,0.f}; m_[i] = -1e30f; l_[i] = 0.f; }

  bf16x8 vv0, vv1;

  STAGE_K(0, 0);
  LOAD_V(0);
  asm volatile("s_waitcnt vmcnt(0)" ::: "memory");
  WRITE_V(0);
  __syncthreads();

  for (int kt = 0; kt <= qt; ++kt) {
    int buf = kt & 1;
    bool pf = (kt < qt);

    f32x4 s[4];
    __builtin_amdgcn_s_setprio(1);
#pragma unroll
    for (int jc = 0; jc < 4; ++jc) {
      s[jc] = (f32x4){0.f, 0.f, 0.f, 0.f};
#pragma unroll
      for (int kc = 0; kc < 2; ++kc) {
        int c = jc * 16 + fr;
        int key = ((c & 7) ^ (c >> 3)) & 7;
        bf16x8 kf = *(const bf16x8*)(Ks[buf] + c * 128 + ((kc * 64 + fb * 16) ^ (key << 4)));
        s[jc] = __builtin_amdgcn_mfma_f32_16x16x32_bf16(qa[kc], kf, s[jc], 0, 0, 0);
      }
    }
    __builtin_amdgcn_s_setprio(0);

    if (pf) {
      STAGE_K(buf ^ 1, kt + 1);
      LOAD_V(kt + 1);
    }

    char* pbase = Ps + w * 2048;
#pragma unroll
    for (int r = 0; r < 4; ++r) {
      float s0 = s[0][r] * SCALE_, s1 = s[1][r] * SCALE_;
      float s2 = s[2][r] * SCALE_, s3 = s[3][r] * SCALE_;
      int qrow = qt * 64 + w * 16 + fb * 4 + r;
      if (kt == qt) {
        int kc0 = kt * 64 + fr;
        if (kc0      > qrow) s0 = -1e30f;
        if (kc0 + 16 > qrow) s1 = -1e30f;
        if (kc0 + 32 > qrow) s2 = -1e30f;
        if (kc0 + 48 > qrow) s3 = -1e30f;
      }
      float mx = fmaxf(fmaxf(s0, s1), fmaxf(s2, s3));
      mx = fmaxf(mx, __shfl_xor(mx, 1, 16));
      mx = fmaxf(mx, __shfl_xor(mx, 2, 16));
      mx = fmaxf(mx, __shfl_xor(mx, 4, 16));
      mx = fmaxf(mx, __shfl_xor(mx, 8, 16));
      float mnew = fmaxf(m_[r], mx);
      float p0 = __expf(s0 - mnew), p1 = __expf(s1 - mnew);
      float p2 = __expf(s2 - mnew), p3 = __expf(s3 - mnew);
      float rs = p0 + p1 + p2 + p3;
      rs += __shfl_xor(rs, 1, 16);
      rs += __shfl_xor(rs, 2, 16);
      rs += __shfl_xor(rs, 4, 16);
      rs += __shfl_xor(rs, 8, 16);
      float scl = __expf(m_[r] - mnew);
      l_[r] = l_[r] * scl + rs;
      m_[r] = mnew;
#pragma unroll
      for (int jd = 0; jd < 4; ++jd) O[jd][r] *= scl;
      int key2 = (r << 4) ^ (fb << 5);
      char* pr_ = pbase + (fb * 4 + r) * 128;
      *(bf16*)(pr_ + (( 0 + fr * 2) ^ key2)) = (bf16)p0;
      *(bf16*)(pr_ + ((32 + fr * 2) ^ key2)) = (bf16)p1;
      *(bf16*)(pr_ + ((64 + fr * 2) ^ key2)) = (bf16)p2;
      *(bf16*)(pr_ + ((96 + fr * 2) ^ key2)) = (bf16)p3;
    }

    __builtin_amdgcn_s_setprio(1);
#pragma unroll
    for (int kc = 0; kc < 2; ++kc) {
      int key2 = ((fr & 3) << 4) ^ ((fr >> 2) << 5);
      bf16x8 pa = *(const bf16x8*)(pbase + fr * 128 + ((kc * 64 + fb * 16) ^ key2));
#pragma unroll
      for (int jd = 0; jd < 4; ++jd) {
        int d = jd * 16 + fr;
        int key = ((d & 7) ^ (d >> 3)) & 7;
        bf16x8 vf = *(const bf16x8*)(Vs[buf] + d * 128 + ((kc * 64 + fb * 16) ^ (key << 4)));
        O[jd] = __builtin_amdgcn_mfma_f32_16x16x32_bf16(pa, vf, O[jd], 0, 0, 0);
      }
    }
    __builtin_amdgcn_s_setprio(0);

    if (pf) {
      asm volatile("s_waitcnt vmcnt(0)" ::: "memory");
      WRITE_V(buf ^ 1);
    }
    __syncthreads();
  }
#undef STAGE_K
#undef LOAD_V
#undef WRITE_V

#pragma unroll
  for (int r = 0; r < 4; ++r) {
    float inv = 1.0f / l_[r];
    float* xp = x + hoff + (size_t)(qt * 64 + w * 16 + fb * 4 + r) * E_;
#pragma unroll
    for (int jd = 0; jd < 4; ++jd) {
      int d = jd * 16 + fr;
      xp[d] += O[jd][r] * inv;
    }
  }
}

// ---------------------------------------------------------------- launch
extern "C" void kernel_launch(void* const* d_in, const int* in_sizes, int n_in,
                              void* d_out, int out_size, void* d_ws, size_t ws_size,
                              hipStream_t stream)
{
  const int*   ids  = (const int*)  d_in[0];
  const float* emb  = (const float*)d_in[1];
  const float* pos  = (const float*)d_in[2];
  const float* wq   = (const float*)d_in[3];
  const float* bq   = (const float*)d_in[4];
  const float* wk   = (const float*)d_in[5];
  const float* bk   = (const float*)d_in[6];
  const float* wv   = (const float*)d_in[7];
  const float* bv   = (const float*)d_in[8];
  const float* w1   = (const float*)d_in[9];
  const float* b1   = (const float*)d_in[10];
  const float* w2   = (const float*)d_in[11];
  const float* b2   = (const float*)d_in[12];
  const float* ln1g = (const float*)d_in[13];
  const float* ln1b = (const float*)d_in[14];
  const float* ln2g = (const float*)d_in[15];
  const float* ln2b = (const float*)d_in[16];
  const float* pw   = (const float*)d_in[17];
  const float* pb   = (const float*)d_in[18];
  float* out = (float*)d_out;

  // ws layout (f32 units), non-overlapping in time:
  //   x   [ 0M,  2M)  f32  BTxE
  //   hb  [ 2M,  3M)  bf16 BTxE      } fpb [2M,4M) = 2 bf16 partials
  //   qb  [ 3M,  4M)  bf16 BTxE      }   (hb,qb dead at FFN2 time)
  //   kb  [ 4M,  5M)  bf16 BTxE
  //   vb  [ 5M,  6M)  bf16 BTxE
  //   ffb [ 6M, 10M)  bf16 BTxFF
  //   lwb [10M,15.5M) bf16 layer weights
  //   hb2 [15.5M,16M) bf16 BTxE  (dead at proj time)
  //   xb  [16M, 17M)  bf16 BTxE
  //   pwb [ 0M,15.625M) bf16 proj weight (all below dead at proj time)
  if (ws_size < (size_t)17 * 1024 * 1024 * 4) return;
  float* ws = (float*)d_ws;
  float* x   = ws;
  bf16*  hb  = (bf16*)(ws + (size_t) 2 * 1024 * 1024);
  bf16*  qb  = (bf16*)(ws + (size_t) 3 * 1024 * 1024);
  bf16*  kb  = (bf16*)(ws + (size_t) 4 * 1024 * 1024);
  bf16*  vb  = (bf16*)(ws + (size_t) 5 * 1024 * 1024);
  bf16*  ffb = (bf16*)(ws + (size_t) 6 * 1024 * 1024);
  bf16*  fpb = (bf16*)(ws + (size_t)2 * 1024 * 1024);
  bf16*  lwb = (bf16*)(ws + (size_t)10 * 1024 * 1024);
  bf16*  hb2 = (bf16*)(ws + (size_t)15 * 1024 * 1024 + 512 * 1024);
  bf16*  xb  = (bf16*)(ws + (size_t)16 * 1024 * 1024);
  bf16*  pwb = (bf16*)ws;
  bf16*  wqt = lwb;
  bf16*  wkt = lwb + (size_t)1 * 1024 * 1024;
  bf16*  wvt = lwb + (size_t)2 * 1024 * 1024;
  bf16*  w1t = lwb + (size_t)3 * 1024 * 1024;
  bf16*  w2t = lwb + (size_t)7 * 1024 * 1024;

  embed_ln_kernel<<<BT_, 256, 0, stream>>>(ids, emb, pos, ln1g, ln1b, x, hb);

  for (int l = 0; l < L_; ++l) {
    const size_t lEE = (size_t)l * E_ * E_;
    const size_t lEF = (size_t)l * E_ * FF_;
    const bf16* hcur = (l == 0) ? hb : hb2;

    convw_all<<<11264, 256, 0, stream>>>(
        wq + lEE, wk + lEE, wv + lEE, w1 + lEF, w2 + lEF,
        wqt, wkt, wvt, w1t, w2t);

    gemm_bf16<0,1><<<dim3(16, E_/128, 3), 256, 0, stream>>>(
        hcur, wqt, wkt, wvt, bq + l*E_, bk + l*E_, bv + l*E_,
        qb, kb, vb, E_, E_, E_);

    attn_kernel<<<dim3(T_/64, B_*H_), 256, 0, stream>>>(qb, kb, vb, x);

    ln_kernel<<<BT_, 256, 0, stream>>>(x, ln2g + l*E_, ln2b + l*E_, hb);

    gemm_bf16<1,1><<<dim3(16, FF_/128, 1), 256, 0, stream>>>(
        hb, w1t, nullptr, nullptr, b1 + (size_t)l*FF_, nullptr, nullptr,
        ffb, nullptr, nullptr, E_, FF_, E_);

    gemm_bf16<0,3><<<dim3(16, E_/128, 2), 256, 0, stream>>>(
        ffb, w2t, nullptr, nullptr, nullptr, nullptr, nullptr,
        fpb, nullptr, nullptr, FF_/2, E_, FF_);
    if (l < L_ - 1) {
      combine_ln_kernel<<<BT_, 256, 0, stream>>>(
          fpb, b2 + l*E_, ln1g + (l+1)*E_, ln1b + (l+1)*E_, x, hb2);
    } else {
      combine_kernel<<<BT_, 256, 0, stream>>>(fpb, b2 + l*E_, x, xb);
    }
  }

  // final projection: whole weight converted, 256^2 BK=64 4-phase GEMM
  convw_kernel<<<dim3(V_/32, E_/32), 256, 0, stream>>>(pw, pwb, E_, V_);
  gemm256_kernel<<<(V_/256) * 8, 512, 0, stream>>>(
      xb, pwb, pb, out, E_, V_);
}